// Round 7
// baseline (464.227 us; speedup 1.0000x reference)
//
#include <hip/hip_runtime.h>
#include <math.h>

#define CC 21
#define HH 512
#define WW 512
#define HWN (HH*WW)
#define CHW (CC*HWN)
#define RAD 7
#define KS 15
#define NITER 5
#define NBKT 16

// fused-iteration tile
#define BX 32
#define BY 16
#define HXW (BX + 2*RAD)   // 46
#define HXH (BY + 2*RAD)   // 30
#define NTHR 512

// norm-kernel tile (proven round-5 structure)
#define TW 128
#define TH 16
#define TWH (TW + 2*RAD)   // 142
#define LSTR 145

#define FEXP(x) __expf(x)
#define FLOG(x) __logf(x)
#define FRCP(x) __builtin_amdgcn_rcpf(x)

// ---------------------------------------------------------------------------
// init: M1t/M2t, diag extracts + flag, taps, zero sums (all parallel)
// ---------------------------------------------------------------------------
__global__ void k_init_small(const float* __restrict__ cm,
                             const float* __restrict__ skw,
                             const float* __restrict__ bkw,
                             float* __restrict__ M1t, float* __restrict__ M2t,
                             float* __restrict__ d1, float* __restrict__ d2,
                             int* __restrict__ dflag,
                             float* __restrict__ kbuf,
                             float* __restrict__ sums) {
    __shared__ int sbad;
    int t = threadIdx.x;
    if (t == 0) sbad = 0;
    __syncthreads();
    if (t < CC*CC) {
        int k = t / CC, c = t % CC;
        float a = 0.f, b = 0.f;
        for (int m = 0; m < CC; ++m) {
            a += cm[c*CC+m] * skw[m*CC+k];
            b += cm[c*CC+m] * bkw[m*CC+k];
        }
        M1t[t] = a; M2t[t] = b;
        if (k != c && (a != 0.f || b != 0.f)) atomicOr(&sbad, 1);
        if (k == c) { d1[c] = a; d2[c] = b; }
    }
    for (int i = t; i < NITER*NBKT*64; i += blockDim.x) sums[i] = 0.f;
    if (t == CC*CC) {
        float w3[KS], w10[KS];
        float s3 = 0.f, s10 = 0.f;
        for (int i = 0; i < KS; ++i) {
            float x = (float)(i - RAD);
            w3[i]  = expf(-0.5f * (x/3.0f)  * (x/3.0f));
            w10[i] = expf(-0.5f * (x/10.0f) * (x/10.0f));
            s3 += w3[i]; s10 += w10[i];
        }
        for (int i = 0; i < KS; ++i) {
            kbuf[i]      = w3[i]  / s3;
            kbuf[KS + i] = w10[i] / s10;
        }
    }
    __syncthreads();
    if (t == 0) dflag[0] = sbad ? 0 : 1;
}

// ---------------------------------------------------------------------------
// guide, spmT, sm0 = softmax(un), clique sums for iter 0.  (q0 == un)
// ---------------------------------------------------------------------------
__global__ void k_init_maps(const float* __restrict__ rgb,
                            const int* __restrict__ spin,
                            const float* __restrict__ un,
                            float* __restrict__ guide,
                            int* __restrict__ spmT,
                            float* __restrict__ sm,
                            const int* __restrict__ spidx,
                            float* __restrict__ sums0) {
    int p = blockIdx.x * blockDim.x + threadIdx.x;
    int h = p / WW, w = p - h*WW;
    float r = rgb[p*3+0] * (1.0f/255.0f);
    float g = rgb[p*3+1] * (1.0f/255.0f);
    float b = rgb[p*3+2] * (1.0f/255.0f);
    guide[p] = FEXP(-0.5f * (r*r + g*g + b*b) / 9.0f);   // theta_beta^2 = 9
    int s = spin[w*HH + h];
    spmT[p] = s;
    float v[CC];
    #pragma unroll
    for (int c = 0; c < CC; ++c) v[c] = un[p*CC + c];
    float mx = v[0];
    #pragma unroll
    for (int c = 1; c < CC; ++c) mx = fmaxf(mx, v[c]);
    float e[CC], ssum = 0.f;
    #pragma unroll
    for (int c = 0; c < CC; ++c) { e[c] = FEXP(v[c] - mx); ssum += e[c]; }
    float inv = FRCP(ssum);
    #pragma unroll
    for (int c = 0; c < CC; ++c) sm[c*HWN + p] = e[c] * inv;

    int sidx = spidx[0];
    bool c1 = (s == sidx), c2 = (s == sidx + 1);
    if (c1 || c2) {
        float* bkt = sums0 + (blockIdx.x & (NBKT-1)) * 64;
        float emx = FEXP(mx);
        if (c1) {
            #pragma unroll
            for (int c = 0; c < CC; ++c) {
                float ev = e[c] * emx;                       // exp(q)
                atomicAdd(&bkt[c], ev - 1.0f);
                float ea = (v[c] == mx) ? emx : ev * emx;    // exp(A_np)
                atomicAdd(&bkt[CC + c], ea - 1.0f);
            }
        } else {
            #pragma unroll
            for (int c = 0; c < CC; ++c) atomicAdd(&bkt[2*CC + c], e[c] * emx - 1.0f);
        }
    }
}

// ---------------------------------------------------------------------------
// norm pass: blur(1) and blur(guide) -> write reciprocals. Round-5 structure.
// ---------------------------------------------------------------------------
__global__ void __launch_bounds__(256, 4)
k_norm(const float* __restrict__ guide,
       float* __restrict__ rsn, float* __restrict__ rbn,
       const float* __restrict__ kbuf) {
    __shared__ float vbs[TH][LSTR];
    __shared__ float vbb[TH][LSTR];
    __shared__ float k3s[KS], k10s[KS];
    int t = threadIdx.x;
    if (t < KS) { k3s[t] = kbuf[t]; k10s[t] = kbuf[KS + t]; }
    __syncthreads();

    int x0 = blockIdx.x * TW;
    int y0 = blockIdx.y * TH;

    for (int u = t; u < 2*TWH; u += 256) {
        int col  = (u < TWH) ? u : u - TWH;
        int half = (u < TWH) ? 0 : 1;
        int xg = x0 - RAD + col;
        bool xok = (xg >= 0 && xg < WW);
        int yb = y0 + half*8;
        float ws_[KS], wb_[KS];
        #pragma unroll
        for (int i = 0; i < KS-1; ++i) {
            int yg = yb - RAD + i;
            bool ok = xok && (yg >= 0) && (yg < HH);
            float v = ok ? 1.0f : 0.f;
            float g = ok ? guide[yg*WW + xg] : 0.f;
            ws_[i] = v; wb_[i] = g;
        }
        #pragma unroll
        for (int y = 0; y < 8; ++y) {
            int yg = yb + y + RAD;
            bool ok = xok && (yg < HH);
            float v = ok ? 1.0f : 0.f;
            float g = ok ? guide[yg*WW + xg] : 0.f;
            ws_[(KS-1+y)%KS] = v; wb_[(KS-1+y)%KS] = g;
            float as = 0.f, ab = 0.f;
            #pragma unroll
            for (int d = 0; d < KS; ++d) {
                as += k3s[d]  * ws_[(y+d)%KS];
                ab += k10s[d] * wb_[(y+d)%KS];
            }
            vbs[half*8 + y][col] = as; vbb[half*8 + y][col] = ab;
        }
    }
    __syncthreads();

    int oy = t & 15;
    int xs = (t >> 4) * 8;
    int rowp = (y0 + oy)*WW + x0 + xs;

    float wS[22], wB[22];
    #pragma unroll
    for (int i = 0; i < 22; ++i) { wS[i] = vbs[oy][xs + i]; wB[i] = vbb[oy][xs + i]; }
    #pragma unroll
    for (int j = 0; j < 8; ++j) {
        float a = 0.f, b = 0.f;
        #pragma unroll
        for (int d = 0; d < KS; ++d) { a += k3s[d] * wS[j + d]; b += k10s[d] * wB[j + d]; }
        rsn[rowp + j] = 1.0f / a;
        rbn[rowp + j] = 1.0f / b;
    }
}

// ---------------------------------------------------------------------------
// FUSED iteration: blur(sm) [v in LDS, h per-pixel] -> pairwise in regs ->
// update -> softmax -> sm_out (+ clique sums for next iter).
// Tile 32x16, 512 threads, 1 px/thread.
// ---------------------------------------------------------------------------
__global__ void __launch_bounds__(NTHR, 4)
k_iter(const float* __restrict__ un,
       const float* __restrict__ qin,    // == un on iter 0, else q (sparse)
       const float* __restrict__ sm_in,
       const float* __restrict__ guide,
       const float* __restrict__ rsn, const float* __restrict__ rbn,
       const float* __restrict__ M1t, const float* __restrict__ M2t,
       const float* __restrict__ d1g, const float* __restrict__ d2g,
       const int* __restrict__ dflag,
       const float* __restrict__ sums_cur, float* __restrict__ sums_next,
       const float* __restrict__ lwg, const float* __restrict__ hwg,
       const int* __restrict__ spmT, const int* __restrict__ spidx, int iter,
       float* __restrict__ q, float* __restrict__ sm_out,
       const float* __restrict__ kbuf,
       float* __restrict__ out, int last) {
    __shared__ float gt[HXH][HXW];
    __shared__ float smt[HXH][HXW];
    __shared__ float vbs[BY][HXW];
    __shared__ float vbb[BY][HXW];
    __shared__ float M1s[CC*CC], M2s[CC*CC];
    __shared__ float slse[3*CC];
    __shared__ float k3s[KS], k10s[KS];
    __shared__ float d1s[CC], d2s[CC];

    int t = threadIdx.x;
    // XCD-chunked block swizzle (bijective: 512 % 8 == 0)
    int lin = blockIdx.x;
    int swz = (lin & 7) * 64 + (lin >> 3);
    int bx = swz & 15, by = swz >> 4;
    int x0 = bx * BX, y0 = by * BY;

    if (t < KS) { k3s[t] = kbuf[t]; k10s[t] = kbuf[KS + t]; }
    if (t >= 32 && t < 32 + CC) { d1s[t-32] = d1g[t-32]; d2s[t-32] = d2g[t-32]; }
    if (t >= 64 && t < 64 + 3*CC) {
        int i = t - 64;
        float s = 0.f;
        #pragma unroll
        for (int b = 0; b < NBKT; ++b) s += sums_cur[b*64 + i];
        slse[i] = FLOG((float)HWN + s);
    }
    int diag = dflag[0];
    if (!diag) {
        for (int i = t; i < CC*CC; i += NTHR) { M1s[i] = M1t[i]; M2s[i] = M2t[i]; }
    }
    for (int l = t; l < HXH*HXW; l += NTHR) {
        int r = l / HXW, cc2 = l - r*HXW;
        int yg = y0 - RAD + r, xg = x0 - RAD + cc2;
        float g = 0.f;
        if (yg >= 0 && yg < HH && xg >= 0 && xg < WW) g = guide[yg*WW + xg];
        gt[r][cc2] = g;
    }

    int tx = t & (BX-1), ty = t >> 5;
    int py = y0 + ty, px = x0 + tx;
    int p = py*WW + px;
    float rsnv = rsn[p], rbnv = rbn[p];

    float acc[CC];
    #pragma unroll
    for (int c = 0; c < CC; ++c) acc[c] = 0.f;

    __syncthreads();

    for (int k = 0; k < CC; ++k) {
        const float* plane = sm_in + (size_t)k*HWN;
        for (int l = t; l < HXH*HXW; l += NTHR) {
            int r = l / HXW, cc2 = l - r*HXW;
            int yg = y0 - RAD + r, xg = x0 - RAD + cc2;
            float v = 0.f;
            if (yg >= 0 && yg < HH && xg >= 0 && xg < WW) v = plane[yg*WW + xg];
            smt[r][cc2] = v;
        }
        __syncthreads();
        for (int u = t; u < BY*HXW; u += NTHR) {
            int ry = u / HXW, cc2 = u - ry*HXW;
            float as = 0.f, ab = 0.f;
            #pragma unroll
            for (int d = 0; d < KS; ++d) {
                float v = smt[ry + d][cc2];
                as += k3s[d] * v;
                ab += k10s[d] * (v * gt[ry + d][cc2]);
            }
            vbs[ry][cc2] = as; vbb[ry][cc2] = ab;
        }
        __syncthreads();
        float s = 0.f, b = 0.f;
        #pragma unroll
        for (int d = 0; d < KS; ++d) {
            s += k3s[d]  * vbs[ty][tx + d];
            b += k10s[d] * vbb[ty][tx + d];
        }
        s *= rsnv; b *= rbnv;
        if (diag) {
            acc[k] = d1s[k]*s + d2s[k]*b;
        } else {
            #pragma unroll
            for (int c = 0; c < CC; ++c)
                acc[c] += M1s[k*CC + c]*s + M2s[k*CC + c]*b;
        }
    }

    // ---- update epilogue (identical math to round-5 k_update) ----
    int sidx = spidx[iter];
    int s = spmT[p];
    float f1 = (s == sidx)     ? 1.f : 0.f;
    float f2 = (s == sidx + 1) ? 1.f : 0.f;
    float hw0 = hwg[0], hw1 = hwg[1], hw2 = hwg[2];
    bool any_clique = __any(f1 != 0.f || f2 != 0.f);
    if (any_clique) {
        float v[CC];
        #pragma unroll
        for (int c = 0; c < CC; ++c) v[c] = qin[p*CC + c];
        float mx = v[0];
        #pragma unroll
        for (int c = 1; c < CC; ++c) mx = fmaxf(mx, v[c]);
        #pragma unroll
        for (int c = 0; c < CC; ++c) {
            float qv = v[c];
            float qmod = qv + ((qv == 0.f) ? 1.f : 0.f);
            float anp = f1 * (qv + mx) - ((f1 != 0.f && qv == mx) ? qv : 0.f);
            float qst = anp + ((anp == 0.f) ? 1.f : 0.f);
            float p1 = f1 * slse[c];
            float p2 = f1 * slse[CC + c];
            float p3 = p1 + f2 * slse[2*CC + c];
            float ft1 = p1 * FRCP(qmod);
            float ft2 = p2 * FRCP(qst);
            float ft3 = p3 * FRCP(qmod);
            float cru = lwg[c]*ft1        + hw0*(1.f - ft1)
                      + lwg[CC + c]*ft2   + hw1*(1.f - ft2)
                      + lwg[2*CC + c]*ft3 + hw2*(1.f - ft3);
            acc[c] = un[p*CC + c] - acc[c] - cru;
        }
    } else {
        float cruc = hw0 + hw1 + hw2;   // all ft == 0
        #pragma unroll
        for (int c = 0; c < CC; ++c)
            acc[c] = un[p*CC + c] - acc[c] - cruc;
    }

    if (!last) {
        int sidx2 = spidx[iter + 1];
        bool c1 = (s == sidx2), c2 = (s == sidx2 + 1);
        if (c1 || c2) {
            #pragma unroll
            for (int c = 0; c < CC; ++c) q[p*CC + c] = acc[c];
        }
        float mx2 = acc[0];
        #pragma unroll
        for (int c = 1; c < CC; ++c) mx2 = fmaxf(mx2, acc[c]);
        float e[CC], ssum = 0.f;
        #pragma unroll
        for (int c = 0; c < CC; ++c) { e[c] = FEXP(acc[c] - mx2); ssum += e[c]; }
        float inv = FRCP(ssum);
        #pragma unroll
        for (int c = 0; c < CC; ++c) sm_out[c*HWN + p] = e[c] * inv;

        if (c1 || c2) {
            float* bkt = sums_next + (lin & (NBKT-1)) * 64;
            float emx = FEXP(mx2);
            if (c1) {
                #pragma unroll
                for (int c = 0; c < CC; ++c) {
                    float ev = e[c] * emx;
                    atomicAdd(&bkt[c], ev - 1.0f);
                    float ea = (acc[c] == mx2) ? emx : ev * emx;
                    atomicAdd(&bkt[CC + c], ea - 1.0f);
                }
            } else {
                #pragma unroll
                for (int c = 0; c < CC; ++c) atomicAdd(&bkt[2*CC + c], e[c] * emx - 1.0f);
            }
        }
    } else {
        #pragma unroll
        for (int c = 0; c < CC; ++c) out[p*CC + c] = acc[c];
    }
}

// ---------------------------------------------------------------------------
extern "C" void kernel_launch(void* const* d_in, const int* in_sizes, int n_in,
                              void* d_out, int out_size, void* d_ws, size_t ws_size,
                              hipStream_t stream) {
    const float* un    = (const float*)d_in[0];
    const float* rgb   = (const float*)d_in[1];
    const int*   spin  = (const int*)  d_in[2];
    const int*   spidx = (const int*)  d_in[3];
    const float* skw   = (const float*)d_in[4];
    const float* bkw   = (const float*)d_in[5];
    const float* lw    = (const float*)d_in[6];
    const float* hwv   = (const float*)d_in[7];
    const float* cm    = (const float*)d_in[8];
    float* out = (float*)d_out;

    float* ws = (float*)d_ws;
    float* q     = ws;                     // pixel-major, sparse-valid
    float* sm    = ws + (size_t)CHW;       // channel-planar
    float* guide = ws + (size_t)2*CHW;
    float* rsn   = guide + HWN;
    float* rbn   = rsn + HWN;
    int*   spmT  = (int*)(rbn + HWN);
    float* M1t   = rbn + 2*(size_t)HWN;    // after spmT (HWN ints)
    float* M2t   = M1t + CC*CC;
    float* d1    = M2t + CC*CC;
    float* d2    = d1 + CC;
    int*   dflag = (int*)(d2 + CC);
    float* kbuf  = d2 + CC + 4;
    float* sums  = kbuf + 2*KS;            // NITER * NBKT * 64 floats

    dim3 blk(256);
    int gpix = HWN / 256;                  // 1024 blocks
    dim3 gnorm(WW/TW, HH/TH, 1);           // 4 x 32

    k_init_small<<<1, 512, 0, stream>>>(cm, skw, bkw, M1t, M2t, d1, d2, dflag,
                                        kbuf, sums);
    k_init_maps<<<gpix, blk, 0, stream>>>(rgb, spin, un, guide, spmT, sm,
                                          spidx, sums);
    k_norm<<<gnorm, blk, 0, stream>>>(guide, rsn, rbn, kbuf);

    for (int it = 0; it < NITER; ++it) {
        int last = (it == NITER - 1) ? 1 : 0;
        float* su  = sums + it*NBKT*64;
        float* sun = last ? nullptr : (sums + (it+1)*NBKT*64);
        const float* qin = (it == 0) ? un : q;
        k_iter<<<(WW/BX)*(HH/BY), NTHR, 0, stream>>>(
            un, qin, sm, guide, rsn, rbn, M1t, M2t, d1, d2, dflag,
            su, sun, lw, hwv, spmT, spidx, it, q, sm, kbuf, out, last);
    }
}